// Round 24
// baseline (809.959 us; speedup 1.0000x reference)
//
#include <hip/hip_runtime.h>

#define BB 16
#define NN 64
#define SS 4096
#define CC 768
#define HH 8
#define HD 96

typedef __attribute__((ext_vector_type(8))) short bf16x8;
typedef __attribute__((ext_vector_type(4))) float f32x4;
typedef __attribute__((ext_vector_type(8))) unsigned short u16x8;

static __device__ __forceinline__ unsigned short f2bf(float x) {
  unsigned u = __float_as_uint(x);
  unsigned r = (u + 0x7fffu + ((u >> 16) & 1u)) >> 16;
  return (unsigned short)r;
}
static __device__ __forceinline__ float bf2f(unsigned short h) {
  return __uint_as_float(((unsigned)h) << 16);
}
// split two fp32 -> packed hi (truncation) + packed lo (truncation of residual).
static __device__ __forceinline__ void split2t(float f0, float f1,
                                               unsigned* hw, unsigned* lw) {
  unsigned u0 = __float_as_uint(f0), u1 = __float_as_uint(f1);
  *hw = (u0 >> 16) | (u1 & 0xffff0000u);
  float l0 = f0 - __uint_as_float(u0 & 0xffff0000u);
  float l1 = f1 - __uint_as_float(u1 & 0xffff0000u);
  unsigned v0 = __float_as_uint(l0), v1 = __float_as_uint(l1);
  *lw = (v0 >> 16) | (v1 & 0xffff0000u);
}

// ---------------------------------------------------------------------------
// K0: 768x768 transpose. 32x32 LDS tiles.
// ---------------------------------------------------------------------------
__global__ __launch_bounds__(256) void k_transpose(
    const float* __restrict__ src, float* __restrict__ dst) {
  __shared__ float tile[32][33];
  const int bx = blockIdx.x % 24, by = blockIdx.x / 24;
  const int tx = threadIdx.x & 31, ty = threadIdx.x >> 5;  // 32 x 8
#pragma unroll
  for (int k = 0; k < 4; ++k)
    tile[ty + k * 8][tx] = src[(size_t)(by * 32 + ty + k * 8) * CC + bx * 32 + tx];
  __syncthreads();
#pragma unroll
  for (int k = 0; k < 4; ++k)
    dst[(size_t)(bx * 32 + ty + k * 8) * CC + by * 32 + tx] = tile[tx][ty + k * 8];
}

// ---------------------------------------------------------------------------
// K1a: q64 = query @ WqT (fp64). Block = 2 rows x 256 j-cols; grid 1536.
// ---------------------------------------------------------------------------
__global__ __launch_bounds__(256) void k_q(
    const float* __restrict__ query, const float* __restrict__ WqT,
    double* __restrict__ q64g) {
  __shared__ double qin[2][CC];
  const int tid = threadIdx.x;
  const int rp = blockIdx.x / 3, cs = blockIdx.x % 3;
  const int r0 = rp * 2;

#pragma unroll
  for (int u = 0; u < 6; ++u) {
    int idx = tid + u * 256;
    int r = idx / CC, c = idx - r * CC;
    qin[r][c] = (double)query[(size_t)(r0 + r) * CC + c];
  }
  __syncthreads();

  const int j = cs * 256 + tid;
  double a0 = 0.0, a1 = 0.0;
  const float* wt = WqT + j;
  for (int e = 0; e < CC; ++e) {
    const double w = (double)wt[(size_t)e * CC];
    a0 += qin[0][e] * w;
    a1 += qin[1][e] * w;
  }
  q64g[(size_t)(r0 + 0) * CC + j] = a0;
  q64g[(size_t)(r0 + 1) * CC + j] = a1;
}

// ---------------------------------------------------------------------------
// K1b: qk fold per head (fp64) + bf16 hi/lo packed writes. Grid 1536.
// ---------------------------------------------------------------------------
__global__ __launch_bounds__(256) void k_fold(
    const double* __restrict__ q64g, const float* __restrict__ Wk,
    double* __restrict__ qk64, unsigned short* __restrict__ qhp,
    unsigned short* __restrict__ qlp) {
  __shared__ double q64l[2][CC];
  const int tid = threadIdx.x;
  const int rp = blockIdx.x / 3, cs3 = blockIdx.x % 3;
  const int r0 = rp * 2;

#pragma unroll
  for (int u = 0; u < 6; ++u) {
    int idx = tid + u * 256;
    int r = idx / CC, c = idx - r * CC;
    q64l[r][c] = q64g[(size_t)(r0 + r) * CC + c];
  }
  __syncthreads();

  const int c = cs3 * 256 + tid;
  const double SC = 0.10206207261596575;  // 96^-0.5
  const int csp = c >> 5, lkc = (c >> 3) & 3, jp = c & 7;

  for (int h = 0; h < HH; ++h) {
    double b0 = 0.0, b1 = 0.0;
    const float* wk = Wk + (size_t)(h * HD) * CC + c;
    const double* qh0 = &q64l[0][h * HD];
    const double* qh1 = &q64l[1][h * HD];
#pragma unroll 4
    for (int dd = 0; dd < HD; ++dd) {
      const double w = (double)wk[(size_t)dd * CC];
      b0 += qh0[dd] * w;
      b1 += qh1[dd] * w;
    }
    b0 *= SC; b1 *= SC;
    double av[2] = {b0, b1};
#pragma unroll
    for (int r = 0; r < 2; ++r) {
      const int row = r0 + r, b_ = row >> 6, n = row & 63;
      const int col512 = h * 64 + n;
      size_t o = ((size_t)(b_ * HH + h) * NN + n) * CC + c;
      qk64[o] = av[r];
      float f = (float)av[r];
      unsigned short hh16 = f2bf(f);
      size_t po = (((size_t)(b_ * 24 + csp) * 32 + (col512 >> 4)) * 64 +
                   (lkc * 16 + (col512 & 15))) * 8 + jp;
      qhp[po] = hh16;
      qlp[po] = f2bf(f - bf2f(hh16));
    }
  }
}

// ---------------------------------------------------------------------------
// K2: MFMA filter, 128-token A-tiles, T14 async-STAGE split restored:
// the 4 staging float4 loads ISSUE at the top of the iteration (hidden
// under both MFMA phases); split2t + LDS writes happen at the tail.
// Same ops/values as r21-23 -> bit-identical outputs.
// ---------------------------------------------------------------------------
#define DELTA 1e-3f

__global__ __launch_bounds__(512, 1) void k_filter_mfma(
    const float* __restrict__ key,
    const unsigned short* __restrict__ qhp, const unsigned short* __restrict__ qlp,
    unsigned char* __restrict__ assign_t, int* __restrict__ susp,
    int* __restrict__ scnt) {
  __shared__ unsigned short khi[2][128][72];   // 36.9KB
  __shared__ unsigned short klo[2][128][72];   // 36.9KB
  const int tid = threadIdx.x;
  const int lane = tid & 63;
  const int wn = tid >> 6;       // wave = head 0..7
  const int bid0 = blockIdx.x;   // 512
  const int swz = (bid0 & 7) * 64 + (bid0 >> 3);   // bijective, XCD-chunked
  const int b = swz >> 5;
  const int s0 = (swz & 31) * 128;
  const int l16 = lane & 15;
  const int lk = lane >> 4;

  f32x4 acc[8][4];
#pragma unroll
  for (int m = 0; m < 8; ++m)
#pragma unroll
    for (int n = 0; n < 4; ++n) acc[m][n] = (f32x4){0.f, 0.f, 0.f, 0.f};

  const float* kbase = key + ((size_t)b * SS + s0) * CC;
  const int srow = tid >> 2, c16 = (tid & 3) * 16;  // 128 rows x 16 floats

#define BBASE(cs) ((((size_t)(b * 24 + (cs)) * 32 + wn * 4) * 64 + lane) * 8)
  // Split + LDS-write of previously loaded x0..x3 (late half of T14 split).
#define STAGE_WRITE(buf)                                                       \
  {                                                                            \
    union { u16x8 v; unsigned w[4]; } ha, la, hb, lb;                          \
    split2t(x0.x, x0.y, &ha.w[0], &la.w[0]);                                   \
    split2t(x0.z, x0.w, &ha.w[1], &la.w[1]);                                   \
    split2t(x1.x, x1.y, &ha.w[2], &la.w[2]);                                   \
    split2t(x1.z, x1.w, &ha.w[3], &la.w[3]);                                   \
    split2t(x2.x, x2.y, &hb.w[0], &lb.w[0]);                                   \
    split2t(x2.z, x2.w, &hb.w[1], &lb.w[1]);                                   \
    split2t(x3.x, x3.y, &hb.w[2], &lb.w[2]);                                   \
    split2t(x3.z, x3.w, &hb.w[3], &lb.w[3]);                                   \
    *(u16x8*)&khi[buf][srow][c16] = ha.v;                                      \
    *(u16x8*)&khi[buf][srow][c16 + 8] = hb.v;                                  \
    *(u16x8*)&klo[buf][srow][c16] = la.v;                                      \
    *(u16x8*)&klo[buf][srow][c16 + 8] = lb.v;                                  \
  }

  // One subchunk's MFMA work for 4 m-tiles starting at m0, with B regs (BH,BL)
#define MHALF(m0, coloff, BH, BL)                                              \
  {                                                                            \
    bf16x8 ah[4], al_[4];                                                      \
    _Pragma("unroll")                                                          \
    for (int mm = 0; mm < 4; ++mm) {                                           \
      ah[mm]  = *(const bf16x8*)&khi[cur][(m0 + mm) * 16 + l16][coloff + lk * 8]; \
      al_[mm] = *(const bf16x8*)&klo[cur][(m0 + mm) * 16 + l16][coloff + lk * 8]; \
    }                                                                          \
    _Pragma("unroll")                                                          \
    for (int mm = 0; mm < 4; ++mm)                                             \
      _Pragma("unroll")                                                        \
      for (int n = 0; n < 4; ++n)                                              \
        acc[m0 + mm][n] = __builtin_amdgcn_mfma_f32_16x16x32_bf16(ah[mm], BH[n], acc[m0 + mm][n], 0, 0, 0); \
    _Pragma("unroll")                                                          \
    for (int mm = 0; mm < 4; ++mm)                                             \
      _Pragma("unroll")                                                        \
      for (int n = 0; n < 4; ++n)                                              \
        acc[m0 + mm][n] = __builtin_amdgcn_mfma_f32_16x16x32_bf16(ah[mm], BL[n], acc[m0 + mm][n], 0, 0, 0); \
    _Pragma("unroll")                                                          \
    for (int mm = 0; mm < 4; ++mm)                                             \
      _Pragma("unroll")                                                        \
      for (int n = 0; n < 4; ++n)                                              \
        acc[m0 + mm][n] = __builtin_amdgcn_mfma_f32_16x16x32_bf16(al_[mm], BH[n], acc[m0 + mm][n], 0, 0, 0); \
  }

  bf16x8 bhA[4], blA[4], bhB[4], blB[4];
  {
    float4 x0, x1, x2, x3;
    const float* sp = kbase + (size_t)srow * CC + c16;
    x0 = *(const float4*)(sp);
    x1 = *(const float4*)(sp + 4);
    x2 = *(const float4*)(sp + 8);
    x3 = *(const float4*)(sp + 12);
    STAGE_WRITE(0);
    const size_t bb = BBASE(0);
#pragma unroll
    for (int n = 0; n < 4; ++n) {
      bhA[n] = *(const bf16x8*)(qhp + bb + (size_t)n * 512);
      blA[n] = *(const bf16x8*)(qlp + bb + (size_t)n * 512);
    }
  }
  __syncthreads();

  for (int t = 0; t < 12; ++t) {
    const int cur = t & 1;
    // ---- T14 early-issue: next tile's 4 global loads launch FIRST ----
    float4 x0, x1, x2, x3;
    if (t < 11) {
      const float* sp = kbase + (size_t)srow * CC + (t + 1) * 64 + c16;
      x0 = *(const float4*)(sp);
      x1 = *(const float4*)(sp + 4);
      x2 = *(const float4*)(sp + 8);
      x3 = *(const float4*)(sp + 12);
    }
    // ================= ss = 0: B buffer A, prefetch B(cs+1) ==============
    {
      const size_t bbn = BBASE(t * 2 + 1);
#pragma unroll
      for (int n = 0; n < 4; ++n) {
        bhB[n] = *(const bf16x8*)(qhp + bbn + (size_t)n * 512);
        blB[n] = *(const bf16x8*)(qlp + bbn + (size_t)n * 512);
      }
      MHALF(0, 0, bhA, blA);
      MHALF(4, 0, bhA, blA);
    }
    // ================= ss = 1: B buffer B, prefetch B(cs+2) ==============
    {
      if (t < 11) {
        const size_t bbn = BBASE(t * 2 + 2);
#pragma unroll
        for (int n = 0; n < 4; ++n) {
          bhA[n] = *(const bf16x8*)(qhp + bbn + (size_t)n * 512);
          blA[n] = *(const bf16x8*)(qlp + bbn + (size_t)n * 512);
        }
      }
      MHALF(0, 32, bhB, blB);
      MHALF(4, 32, bhB, blB);
    }

    // ---- T14 late-write: split + LDS store (loads long since landed) ----
    if (t < 11) {
      STAGE_WRITE(cur ^ 1);
    }
    __syncthreads();
  }
#undef MHALF
#undef STAGE_WRITE
#undef BBASE

  // Reduction: C/D layout col = l16 (group), row = lk*4 + reg (token).
#pragma unroll
  for (int m = 0; m < 8; ++m) {
    const int tokbase = s0 + m * 16 + lk * 4;
#pragma unroll
    for (int r = 0; r < 4; ++r) {
      const int tok = tokbase + r;
      float m1 = -3.402823466e38f, m2 = -3.402823466e38f;
      int i1 = 0;
#pragma unroll
      for (int n = 0; n < 4; ++n) {
        float v = acc[m][n][r];
        int g = n * 16 + l16;
        if (v > m1) { m2 = m1; m1 = v; i1 = g; }
        else if (v > m2) m2 = v;
      }
#pragma unroll
      for (int off = 1; off <= 8; off <<= 1) {
        float om1 = __shfl_xor(m1, off);
        float om2 = __shfl_xor(m2, off);
        int oi1 = __shfl_xor(i1, off);
        if (om1 > m1 || (om1 == m1 && oi1 < i1)) {
          m2 = fmaxf(m1, fmaxf(m2, om2));
          m1 = om1; i1 = oi1;
        } else {
          m2 = fmaxf(om1, fmaxf(m2, om2));
        }
      }
      if (l16 == 0) {
        const int bh2 = b * 8 + wn;
        assign_t[((size_t)b * SS + tok) * 8 + wn] = (unsigned char)i1;
        if (m1 - m2 < DELTA) {
          int w = atomicAdd(&scnt[bh2], 1);
          susp[(size_t)bh2 * SS + w] = tok;
        }
      }
    }
  }
}

// ---------------------------------------------------------------------------
// K3: exact fp64 rescore, 16-suspect batches.
// ---------------------------------------------------------------------------
__global__ __launch_bounds__(256) void k_rescore(
    const float* __restrict__ key, const double* __restrict__ qk64,
    const int* __restrict__ susp, const int* __restrict__ scnt,
    unsigned char* __restrict__ assign_t) {
  __shared__ float krow[16][CC];     // 48KB
  __shared__ double l64[16][64];     // 8KB
  const int bh = blockIdx.x;
  const int cnt = scnt[bh];
  if (cnt == 0) return;
  const int b = bh >> 3, h = bh & 7;
  const int tid = threadIdx.x;
  const int n = tid >> 2, q = tid & 3;
  const double* qrow = qk64 + ((size_t)bh * NN + n) * CC + q * 192;

  for (int i0 = 0; i0 < cnt; i0 += 16) {
    const int nb = (cnt - i0 < 16) ? (cnt - i0) : 16;
    for (int r = 0; r < nb; ++r) {
      const int s = susp[(size_t)bh * SS + i0 + r];
      for (int u = tid; u < CC; u += 256)
        krow[r][u] = key[((size_t)b * SS + s) * CC + u];
    }
    __syncthreads();

    double acc[16];
#pragma unroll
    for (int r = 0; r < 16; ++r) acc[r] = 0.0;
    for (int c4 = 0; c4 < 48; ++c4) {
      const double w0 = qrow[c4 * 4 + 0];
      const double w1 = qrow[c4 * 4 + 1];
      const double w2 = qrow[c4 * 4 + 2];
      const double w3 = qrow[c4 * 4 + 3];
#pragma unroll
      for (int r = 0; r < 16; ++r) {
        float4 k4 = *(const float4*)&krow[r][q * 192 + c4 * 4];
        acc[r] += w0 * (double)k4.x;
        acc[r] += w1 * (double)k4.y;
        acc[r] += w2 * (double)k4.z;
        acc[r] += w3 * (double)k4.w;
      }
    }
#pragma unroll
    for (int r = 0; r < 16; ++r) {
      acc[r] += __shfl_xor(acc[r], 1);
      acc[r] += __shfl_xor(acc[r], 2);
    }
    if (q == 0) {
#pragma unroll
      for (int r = 0; r < 16; ++r) l64[r][n] = acc[r];
    }
    __syncthreads();
    if (tid < nb) {
      double best = l64[tid][0];
      int bi = 0;
      for (int n2 = 1; n2 < 64; ++n2)
        if (l64[tid][n2] > best) { best = l64[tid][n2]; bi = n2; }
      const int s = susp[(size_t)bh * SS + i0 + tid];
      assign_t[((size_t)b * SS + s) * 8 + h] = (unsigned char)bi;
    }
    __syncthreads();
  }
}

// ---------------------------------------------------------------------------
// K4: per-(b,h,n) token counts. Block per bh.
// ---------------------------------------------------------------------------
__global__ __launch_bounds__(256) void k_counts(
    const unsigned char* __restrict__ assign_t, int* __restrict__ counts) {
  __shared__ int hist[64];
  const int bh = blockIdx.x;
  const int b = bh >> 3, h = bh & 7;
  const int tid = threadIdx.x;
  if (tid < 64) hist[tid] = 0;
  __syncthreads();
  for (int s = tid; s < SS; s += 256)
    atomicAdd(&hist[assign_t[((size_t)b * SS + s) * 8 + h]], 1);
  __syncthreads();
  if (tid < 64) counts[bh * 64 + tid] = hist[tid];
}

// ---------------------------------------------------------------------------
// K4b: 8-batch key slice -> bf16 (RNE). Called twice.
// ---------------------------------------------------------------------------
__global__ __launch_bounds__(256) void k_convert(
    const float* __restrict__ keyhalf, unsigned short* __restrict__ kb16) {
  const int n8 = 8 * SS * CC / 8;    // 3,145,728 u16x8 outputs
  int i = blockIdx.x * 256 + threadIdx.x;
  const int stride = gridDim.x * 256;
  for (; i < n8; i += stride) {
    float4 a = ((const float4*)keyhalf)[i * 2];
    float4 b = ((const float4*)keyhalf)[i * 2 + 1];
    u16x8 r;
    r[0] = f2bf(a.x); r[1] = f2bf(a.y); r[2] = f2bf(a.z); r[3] = f2bf(a.w);
    r[4] = f2bf(b.x); r[5] = f2bf(b.y); r[6] = f2bf(b.z); r[7] = f2bf(b.w);
    *(u16x8*)(kb16 + (size_t)i * 8) = r;
  }
}

// ---------------------------------------------------------------------------
// K5: stable counting-sort permutation. One wave per (b,h).
// ---------------------------------------------------------------------------
__global__ __launch_bounds__(64) void k_rank(
    const unsigned char* __restrict__ assign_t, const int* __restrict__ counts,
    int* __restrict__ offsets, int* __restrict__ perm) {
  __shared__ int base[64];
  const int bh = blockIdx.x;     // b*8 + h
  const int b = bh >> 3, h = bh & 7;
  const int lane = threadIdx.x;

  int cn = counts[bh * 64 + lane];
  int off = cn;
#pragma unroll
  for (int d = 1; d < 64; d <<= 1) {
    int t = __shfl_up(off, d);
    if (lane >= d) off += t;
  }
  off -= cn;  // exclusive prefix
  offsets[bh * 64 + lane] = off;
  base[lane] = off;

  for (int c = 0; c < SS / 64; ++c) {
    const int s = c * 64 + lane;
    const int g = (int)assign_t[((size_t)b * SS + s) * 8 + h];
    unsigned long long m = ~0ull;
#pragma unroll
    for (int k = 0; k < 6; ++k) {
      unsigned long long bk = __ballot((g >> k) & 1);
      m &= ((g >> k) & 1) ? bk : ~bk;
    }
    const int leader = __ffsll((unsigned long long)m) - 1;
    const int rankin = __popcll(m & ((1ull << lane) - 1ull));
    int baseo = 0;
    if (lane == leader) {
      baseo = base[g];
      base[g] = baseo + __popcll(m);
    }
    baseo = __shfl(baseo, leader);
    perm[(size_t)bh * SS + baseo + rankin] = s;
  }
}

// ---------------------------------------------------------------------------
// K6: permuted gather over bf16 half-copy (8 batches). One wave per (b,h,n).
// ---------------------------------------------------------------------------
__global__ __launch_bounds__(64) void k_gatherp(
    const unsigned short* __restrict__ kb16, const int* __restrict__ perm,
    const int* __restrict__ offsets, const int* __restrict__ counts,
    float* __restrict__ gsum, int b0) {
  const int bid = blockIdx.x;        // local: bl*512 + h*64 + n, bl in [0,8)
  const int bl = bid >> 9;           // local batch
  const int gbid = b0 * 512 + bid;   // global (b*512 + h*64 + n)
  const int bh = gbid >> 6;
  const int lane = threadIdx.x;

  const int off = offsets[gbid];
  const int cnt = counts[gbid];
  const int* pl = perm + (size_t)bh * SS + off;
  const unsigned short* kb = kb16 + (size_t)bl * SS * CC;

  float4 a0 = {0.f, 0.f, 0.f, 0.f}, b0v = a0, c0 = a0;
  int j = 0;
  for (; j + 3 < cnt; j += 4) {
    const int s0 = pl[j], s1 = pl[j + 1], s2 = pl[j + 2], s3 = pl[j + 3];
    const ushort4* k0 = (const ushort4*)(kb + (size_t)s0 * CC);
    const ushort4* k1 = (const ushort4*)(kb + (size_t)s1 * CC);
    const ushort4* k2 = (const ushort4*)(kb + (size_t)s2 * CC);
    const ushort4* k3 = (const ushort4*)(kb + (size_t)s3 * CC);
    ushort4 x0 = k0[lane], x1 = k0[lane + 64], x2 = k0[lane + 128];
    ushort4 y0 = k1[lane], y1 = k1[lane + 64], y2 = k1[lane + 128];
    ushort4 z0 = k2[lane], z1 = k2[lane + 64], z2 = k2[lane + 128];
    ushort4 w0 = k3[lane], w1 = k3[lane + 64], w2 = k3[lane + 128];
    a0.x += bf2f(x0.x); a0.y += bf2f(x0.y); a0.z += bf2f(x0.z); a0.w += bf2f(x0.w);
    b0v.x += bf2f(x1.x); b0v.y += bf2f(x1.y); b0v.z += bf2f(x1.z); b0v.w += bf2f(x1.w);
    c0.x += bf2f(x2.x); c0.y += bf2f(x2.y); c0.z += bf2f(x2.z); c0.w += bf2f(x2.w);
    a0.x += bf2f(y0.x); a0.y += bf2f(y0.y); a0.z += bf2f(y0.z); a0.w += bf2f(y0.w);
    b0v.x += bf2f(y1.x); b0v.y += bf2f(y1.y); b0v.z += bf2f(y1.z); b0v.w += bf2f(y1.w);
    c0.x += bf2f(y2.x); c0.y += bf2f(y2.y); c0.z += bf2f(y2.z); c0.w += bf2f(y2.w);
    a0.x += bf2f(z0.x); a0.y += bf2f(z0.y); a0.z += bf2f(z0.z); a0.w += bf2f(z0.w);
    b0v.x += bf2f(z1.x); b0v.y += bf2f(z1.y); b0v.z += bf2f(z1.z); b0v.w += bf2f(z1.w);
    c0.x += bf2f(z2.x); c0.y += bf2f(z2.y); c0.z += bf2f(z2.z); c0.w += bf2f(z2.w);
    a0.x += bf2f(w0.x); a0.y += bf2f(w0.y); a0.z += bf2f(w0.z); a0.w += bf2f(w0.w);
    b0v.x += bf2f(w1.x); b0v.y += bf2f(w1.y); b0v.z += bf2f(w1.z); b0v.w += bf2f(w1.w);
    c0.x += bf2f(w2.x); c0.y += bf2f(w2.y); c0.z += bf2f(w2.z); c0.w += bf2f(w2.w);
  }
  for (; j < cnt; ++j) {
    const int s0 = pl[j];
    const ushort4* k0 = (const ushort4*)(kb + (size_t)s0 * CC);
    ushort4 x0 = k0[lane], x1 = k0[lane + 64], x2 = k0[lane + 128];
    a0.x += bf2f(x0.x); a0.y += bf2f(x0.y); a0.z += bf2f(x0.z); a0.w += bf2f(x0.w);
    b0v.x += bf2f(x1.x); b0v.y += bf2f(x1.y); b0v.z += bf2f(x1.z); b0v.w += bf2f(x1.w);
    c0.x += bf2f(x2.x); c0.y += bf2f(x2.y); c0.z += bf2f(x2.z); c0.w += bf2f(x2.w);
  }
  float4* go = (float4*)(gsum + (size_t)gbid * CC);
  go[lane] = a0; go[lane + 64] = b0v; go[lane + 128] = c0;
}

// ---------------------------------------------------------------------------
// K7a: vr = renorm(gs) @ WvT. Block = 2 rows x 256 j-cols; grid 1536.
// ---------------------------------------------------------------------------
__global__ __launch_bounds__(256) void k_v(
    const float* __restrict__ gsum, const int* __restrict__ counts,
    const float* __restrict__ WvT, float* __restrict__ vrg) {
  __shared__ float gs[2][HH][CC];   // 48KB
  const int tid = threadIdx.x;
  const int rp = blockIdx.x / 3, cs = blockIdx.x % 3;
  const int r0 = rp * 2;

  for (int r = 0; r < 2; ++r) {
    int row = r0 + r, b = row >> 6, n = row & 63;
    for (int h = 0; h < HH; ++h) {
      const float sc = 1.f / (float)(counts[(b * HH + h) * NN + n] + 1);
      const float* src = gsum + ((size_t)(b * HH + h) * NN + n) * CC;
      for (int m = 0; m < 3; ++m)
        gs[r][h][tid + m * 256] = src[tid + m * 256] * sc;
    }
  }
  __syncthreads();

  const int j = cs * 256 + tid;
  const int hj = j / HD;
  float a0 = 0.f, a1 = 0.f;
  const float* wt = WvT + j;
  for (int e4 = 0; e4 < CC / 4; ++e4) {
    const int e = e4 * 4;
    float4 g0 = *(const float4*)&gs[0][hj][e];
    float4 g1 = *(const float4*)&gs[1][hj][e];
    const float w0 = wt[(size_t)e * CC];
    const float w1 = wt[(size_t)(e + 1) * CC];
    const float w2 = wt[(size_t)(e + 2) * CC];
    const float w3 = wt[(size_t)(e + 3) * CC];
    a0 = fmaf(g0.x, w0, a0); a0 = fmaf(g0.y, w1, a0);
    a0 = fmaf(g0.z, w2, a0); a0 = fmaf(g0.w, w3, a0);
    a1 = fmaf(g1.x, w0, a1); a1 = fmaf(g1.y, w1, a1);
    a1 = fmaf(g1.z, w2, a1); a1 = fmaf(g1.w, w3, a1);
  }
  vrg[(size_t)(r0 + 0) * CC + j] = a0;
  vrg[(size_t)(r0 + 1) * CC + j] = a1;
}

// ---------------------------------------------------------------------------
// K7b: out = vr @ WoT + bo. Block = 2 rows x 256 j-cols; grid 1536.
// ---------------------------------------------------------------------------
__global__ __launch_bounds__(256) void k_o(
    const float* __restrict__ vrg, const float* __restrict__ WoT,
    const float* __restrict__ bo, float* __restrict__ out) {
  __shared__ float vr[2][CC];   // 6KB
  const int tid = threadIdx.x;
  const int rp = blockIdx.x / 3, cs = blockIdx.x % 3;
  const int r0 = rp * 2;

#pragma unroll
  for (int u = 0; u < 6; ++u) {
    int idx = tid + u * 256;
    int r = idx / CC, c = idx - r * CC;
    vr[r][c] = vrg[(size_t)(r0 + r) * CC + c];
  }
  __syncthreads();

  const int j = cs * 256 + tid;
  float a0 = bo[j], a1 = a0;
  const float* wt = WoT + j;
  for (int e4 = 0; e4 < CC / 4; ++e4) {
    const int e = e4 * 4;
    float4 v0 = *(const float4*)&vr[0][e];
    float4 v1 = *(const float4*)&vr[1][e];
    const float w0 = wt[(size_t)e * CC];
    const float w1 = wt[(size_t)(e + 1) * CC];
    const float w2 = wt[(size_t)(e + 2) * CC];
    const float w3 = wt[(size_t)(e + 3) * CC];
    a0 = fmaf(v0.x, w0, a0); a0 = fmaf(v0.y, w1, a0);
    a0 = fmaf(v0.z, w2, a0); a0 = fmaf(v0.w, w3, a0);
    a1 = fmaf(v1.x, w0, a1); a1 = fmaf(v1.y, w1, a1);
    a1 = fmaf(v1.z, w2, a1); a1 = fmaf(v1.w, w3, a1);
  }
  out[(size_t)(r0 + 0) * CC + j] = a0;
  out[(size_t)(r0 + 1) * CC + j] = a1;
}

// ---------------------------------------------------------------------------
extern "C" void kernel_launch(void* const* d_in, const int* in_sizes, int n_in,
                              void* d_out, int out_size, void* d_ws, size_t ws_size,
                              hipStream_t stream) {
  const float* query = (const float*)d_in[0];
  const float* key   = (const float*)d_in[1];
  const float* Wq    = (const float*)d_in[2];
  const float* Wk    = (const float*)d_in[3];
  const float* Wv    = (const float*)d_in[4];
  const float* Wo    = (const float*)d_in[5];
  const float* bo    = (const float*)d_in[6];
  float* out = (float*)d_out;

  char* ws = (char*)d_ws;
  // layout (bytes), high-water 96,797,184 (< round-1-proven 103MB). Aliasing:
  //   qk64 [0, 48MB)       : live k_fold -> rescore
  //   kb16 [0, 48MB)       : 8-batch bf16 key half, written AFTER rescore, 2x
  //   qhp/qlp [48, 72MB)   : live k_fold -> filter
  //   gsum [48, 72MB)      : aliases qhp/qlp, written by gatherp AFTER filter
  double* qk64           = (double*)(ws);                    // 50331648
  unsigned short* kb16   = (unsigned short*)(ws);            // 50331648 (alias)
  unsigned short* qhp    = (unsigned short*)(ws + 50331648); // 12582912
  unsigned short* qlp    = (unsigned short*)(ws + 62914560); // 12582912
  float* gsum            = (float*)(ws + 50331648);          // 25165824 (alias)
  unsigned char* assign_t= (unsigned char*)(ws + 75497472);  // 524288
  int* susp              = (int*)(ws + 76021760);            // 2097152
  int* scnt              = (int*)(ws + 78118912);            // 512
  int* counts            = (int*)(ws + 78119424);            // 32768
  int* offsets           = (int*)(ws + 78152192);            // 32768
  int* perm              = (int*)(ws + 78184960);            // 2097152
  float* WqT             = (float*)(ws + 80282112);          // 2359296
  float* WvT             = (float*)(ws + 82641408);          // 2359296
  float* WoT             = (float*)(ws + 85000704);          // 2359296
  double* q64g           = (double*)(ws + 87360000);         // 6291456
  float* vrg             = (float*)(ws + 93651456);          // 3145728 -> end 96797184

  hipMemsetAsync(scnt, 0, 512, stream);
  k_transpose<<<576, 256, 0, stream>>>(Wq, WqT);
  k_transpose<<<576, 256, 0, stream>>>(Wv, WvT);
  k_transpose<<<576, 256, 0, stream>>>(Wo, WoT);
  k_q<<<1536, 256, 0, stream>>>(query, WqT, q64g);
  k_fold<<<1536, 256, 0, stream>>>(q64g, Wk, qk64, qhp, qlp);
  k_filter_mfma<<<512, 512, 0, stream>>>(key, qhp, qlp, assign_t, susp, scnt);
  k_rescore<<<128, 256, 0, stream>>>(key, qk64, susp, scnt, assign_t);
  k_counts<<<128, 256, 0, stream>>>(assign_t, counts);
  k_rank<<<128, 64, 0, stream>>>(assign_t, counts, offsets, perm);
  // phase A: batches 0..7 (kb16 overwrites dead qk64)
  k_convert<<<1024, 256, 0, stream>>>(key, kb16);
  k_gatherp<<<4096, 64, 0, stream>>>(kb16, perm, offsets, counts, gsum, 0);
  // phase B: batches 8..15
  k_convert<<<1024, 256, 0, stream>>>(key + (size_t)8 * SS * CC, kb16);
  k_gatherp<<<4096, 64, 0, stream>>>(kb16, perm, offsets, counts, gsum, 8);
  k_v<<<1536, 256, 0, stream>>>(gsum, counts, WvT, vrg);
  k_o<<<1536, 256, 0, stream>>>(vrg, WoT, bo, out);
}

// Round 25
// 791.240 us; speedup vs baseline: 1.0237x; 1.0237x over previous
//
#include <hip/hip_runtime.h>

#define BB 16
#define NN 64
#define SS 4096
#define CC 768
#define HH 8
#define HD 96

typedef __attribute__((ext_vector_type(8))) short bf16x8;
typedef __attribute__((ext_vector_type(4))) float f32x4;
typedef __attribute__((ext_vector_type(8))) unsigned short u16x8;

static __device__ __forceinline__ unsigned short f2bf(float x) {
  unsigned u = __float_as_uint(x);
  unsigned r = (u + 0x7fffu + ((u >> 16) & 1u)) >> 16;
  return (unsigned short)r;
}
static __device__ __forceinline__ float bf2f(unsigned short h) {
  return __uint_as_float(((unsigned)h) << 16);
}
// split two fp32 -> packed hi (truncation) + packed lo (truncation of residual).
static __device__ __forceinline__ void split2t(float f0, float f1,
                                               unsigned* hw, unsigned* lw) {
  unsigned u0 = __float_as_uint(f0), u1 = __float_as_uint(f1);
  *hw = (u0 >> 16) | (u1 & 0xffff0000u);
  float l0 = f0 - __uint_as_float(u0 & 0xffff0000u);
  float l1 = f1 - __uint_as_float(u1 & 0xffff0000u);
  unsigned v0 = __float_as_uint(l0), v1 = __float_as_uint(l1);
  *lw = (v0 >> 16) | (v1 & 0xffff0000u);
}

// ---------------------------------------------------------------------------
// K0: 768x768 transpose. 32x32 LDS tiles.
// ---------------------------------------------------------------------------
__global__ __launch_bounds__(256) void k_transpose(
    const float* __restrict__ src, float* __restrict__ dst) {
  __shared__ float tile[32][33];
  const int bx = blockIdx.x % 24, by = blockIdx.x / 24;
  const int tx = threadIdx.x & 31, ty = threadIdx.x >> 5;  // 32 x 8
#pragma unroll
  for (int k = 0; k < 4; ++k)
    tile[ty + k * 8][tx] = src[(size_t)(by * 32 + ty + k * 8) * CC + bx * 32 + tx];
  __syncthreads();
#pragma unroll
  for (int k = 0; k < 4; ++k)
    dst[(size_t)(bx * 32 + ty + k * 8) * CC + by * 32 + tx] = tile[tx][ty + k * 8];
}

// ---------------------------------------------------------------------------
// K1a: q64 = query @ WqT (fp64). Block = 2 rows x 256 j-cols; grid 1536.
// ---------------------------------------------------------------------------
__global__ __launch_bounds__(256) void k_q(
    const float* __restrict__ query, const float* __restrict__ WqT,
    double* __restrict__ q64g) {
  __shared__ double qin[2][CC];
  const int tid = threadIdx.x;
  const int rp = blockIdx.x / 3, cs = blockIdx.x % 3;
  const int r0 = rp * 2;

#pragma unroll
  for (int u = 0; u < 6; ++u) {
    int idx = tid + u * 256;
    int r = idx / CC, c = idx - r * CC;
    qin[r][c] = (double)query[(size_t)(r0 + r) * CC + c];
  }
  __syncthreads();

  const int j = cs * 256 + tid;
  double a0 = 0.0, a1 = 0.0;
  const float* wt = WqT + j;
  for (int e = 0; e < CC; ++e) {
    const double w = (double)wt[(size_t)e * CC];
    a0 += qin[0][e] * w;
    a1 += qin[1][e] * w;
  }
  q64g[(size_t)(r0 + 0) * CC + j] = a0;
  q64g[(size_t)(r0 + 1) * CC + j] = a1;
}

// ---------------------------------------------------------------------------
// K1b: qk fold per head (fp64) + bf16 hi/lo packed writes. Grid 1536.
// ---------------------------------------------------------------------------
__global__ __launch_bounds__(256) void k_fold(
    const double* __restrict__ q64g, const float* __restrict__ Wk,
    double* __restrict__ qk64, unsigned short* __restrict__ qhp,
    unsigned short* __restrict__ qlp) {
  __shared__ double q64l[2][CC];
  const int tid = threadIdx.x;
  const int rp = blockIdx.x / 3, cs3 = blockIdx.x % 3;
  const int r0 = rp * 2;

#pragma unroll
  for (int u = 0; u < 6; ++u) {
    int idx = tid + u * 256;
    int r = idx / CC, c = idx - r * CC;
    q64l[r][c] = q64g[(size_t)(r0 + r) * CC + c];
  }
  __syncthreads();

  const int c = cs3 * 256 + tid;
  const double SC = 0.10206207261596575;  // 96^-0.5
  const int csp = c >> 5, lkc = (c >> 3) & 3, jp = c & 7;

  for (int h = 0; h < HH; ++h) {
    double b0 = 0.0, b1 = 0.0;
    const float* wk = Wk + (size_t)(h * HD) * CC + c;
    const double* qh0 = &q64l[0][h * HD];
    const double* qh1 = &q64l[1][h * HD];
#pragma unroll 4
    for (int dd = 0; dd < HD; ++dd) {
      const double w = (double)wk[(size_t)dd * CC];
      b0 += qh0[dd] * w;
      b1 += qh1[dd] * w;
    }
    b0 *= SC; b1 *= SC;
    double av[2] = {b0, b1};
#pragma unroll
    for (int r = 0; r < 2; ++r) {
      const int row = r0 + r, b_ = row >> 6, n = row & 63;
      const int col512 = h * 64 + n;
      size_t o = ((size_t)(b_ * HH + h) * NN + n) * CC + c;
      qk64[o] = av[r];
      float f = (float)av[r];
      unsigned short hh16 = f2bf(f);
      size_t po = (((size_t)(b_ * 24 + csp) * 32 + (col512 >> 4)) * 64 +
                   (lkc * 16 + (col512 & 15))) * 8 + jp;
      qhp[po] = hh16;
      qlp[po] = f2bf(f - bf2f(hh16));
    }
  }
}

// ---------------------------------------------------------------------------
// K2: MFMA filter, 128-token A-tiles (round-21/23 structure, session best:
// 180us, MfmaUtil 37%). Tail STAGE; B register double-buffer; XCD swizzle.
// r24 showed T14 early-issue HURTS here (128-VGPR cap -> more spill).
// ---------------------------------------------------------------------------
#define DELTA 1e-3f

__global__ __launch_bounds__(512, 1) void k_filter_mfma(
    const float* __restrict__ key,
    const unsigned short* __restrict__ qhp, const unsigned short* __restrict__ qlp,
    unsigned char* __restrict__ assign_t, int* __restrict__ susp,
    int* __restrict__ scnt) {
  __shared__ unsigned short khi[2][128][72];   // 36.9KB
  __shared__ unsigned short klo[2][128][72];   // 36.9KB
  const int tid = threadIdx.x;
  const int lane = tid & 63;
  const int wn = tid >> 6;       // wave = head 0..7
  const int bid0 = blockIdx.x;   // 512
  const int swz = (bid0 & 7) * 64 + (bid0 >> 3);   // bijective, XCD-chunked
  const int b = swz >> 5;
  const int s0 = (swz & 31) * 128;
  const int l16 = lane & 15;
  const int lk = lane >> 4;

  f32x4 acc[8][4];
#pragma unroll
  for (int m = 0; m < 8; ++m)
#pragma unroll
    for (int n = 0; n < 4; ++n) acc[m][n] = (f32x4){0.f, 0.f, 0.f, 0.f};

  const float* kbase = key + ((size_t)b * SS + s0) * CC;
  const int srow = tid >> 2, c16 = (tid & 3) * 16;  // 128 rows x 16 floats

#define BBASE(cs) ((((size_t)(b * 24 + (cs)) * 32 + wn * 4) * 64 + lane) * 8)
#define STAGE(buf, cb)                                                         \
  {                                                                            \
    const float* sp = kbase + (size_t)srow * CC + (cb) + c16;                  \
    float4 x0 = *(const float4*)(sp);                                          \
    float4 x1 = *(const float4*)(sp + 4);                                      \
    float4 x2 = *(const float4*)(sp + 8);                                      \
    float4 x3 = *(const float4*)(sp + 12);                                     \
    union { u16x8 v; unsigned w[4]; } ha, la, hb, lb;                          \
    split2t(x0.x, x0.y, &ha.w[0], &la.w[0]);                                   \
    split2t(x0.z, x0.w, &ha.w[1], &la.w[1]);                                   \
    split2t(x1.x, x1.y, &ha.w[2], &la.w[2]);                                   \
    split2t(x1.z, x1.w, &ha.w[3], &la.w[3]);                                   \
    split2t(x2.x, x2.y, &hb.w[0], &lb.w[0]);                                   \
    split2t(x2.z, x2.w, &hb.w[1], &lb.w[1]);                                   \
    split2t(x3.x, x3.y, &hb.w[2], &lb.w[2]);                                   \
    split2t(x3.z, x3.w, &hb.w[3], &lb.w[3]);                                   \
    *(u16x8*)&khi[buf][srow][c16] = ha.v;                                      \
    *(u16x8*)&khi[buf][srow][c16 + 8] = hb.v;                                  \
    *(u16x8*)&klo[buf][srow][c16] = la.v;                                      \
    *(u16x8*)&klo[buf][srow][c16 + 8] = lb.v;                                  \
  }

  // One subchunk's MFMA work for 4 m-tiles starting at m0, with B regs (BH,BL)
#define MHALF(m0, coloff, BH, BL)                                              \
  {                                                                            \
    bf16x8 ah[4], al_[4];                                                      \
    _Pragma("unroll")                                                          \
    for (int mm = 0; mm < 4; ++mm) {                                           \
      ah[mm]  = *(const bf16x8*)&khi[cur][(m0 + mm) * 16 + l16][coloff + lk * 8]; \
      al_[mm] = *(const bf16x8*)&klo[cur][(m0 + mm) * 16 + l16][coloff + lk * 8]; \
    }                                                                          \
    _Pragma("unroll")                                                          \
    for (int mm = 0; mm < 4; ++mm)                                             \
      _Pragma("unroll")                                                        \
      for (int n = 0; n < 4; ++n)                                              \
        acc[m0 + mm][n] = __builtin_amdgcn_mfma_f32_16x16x32_bf16(ah[mm], BH[n], acc[m0 + mm][n], 0, 0, 0); \
    _Pragma("unroll")                                                          \
    for (int mm = 0; mm < 4; ++mm)                                             \
      _Pragma("unroll")                                                        \
      for (int n = 0; n < 4; ++n)                                              \
        acc[m0 + mm][n] = __builtin_amdgcn_mfma_f32_16x16x32_bf16(ah[mm], BL[n], acc[m0 + mm][n], 0, 0, 0); \
    _Pragma("unroll")                                                          \
    for (int mm = 0; mm < 4; ++mm)                                             \
      _Pragma("unroll")                                                        \
      for (int n = 0; n < 4; ++n)                                              \
        acc[m0 + mm][n] = __builtin_amdgcn_mfma_f32_16x16x32_bf16(al_[mm], BH[n], acc[m0 + mm][n], 0, 0, 0); \
  }

  bf16x8 bhA[4], blA[4], bhB[4], blB[4];
  {
    STAGE(0, 0);
    const size_t bb = BBASE(0);
#pragma unroll
    for (int n = 0; n < 4; ++n) {
      bhA[n] = *(const bf16x8*)(qhp + bb + (size_t)n * 512);
      blA[n] = *(const bf16x8*)(qlp + bb + (size_t)n * 512);
    }
  }
  __syncthreads();

  for (int t = 0; t < 12; ++t) {
    const int cur = t & 1;
    // ================= ss = 0: B buffer A, prefetch B(cs+1) ==============
    {
      const size_t bbn = BBASE(t * 2 + 1);
#pragma unroll
      for (int n = 0; n < 4; ++n) {
        bhB[n] = *(const bf16x8*)(qhp + bbn + (size_t)n * 512);
        blB[n] = *(const bf16x8*)(qlp + bbn + (size_t)n * 512);
      }
      MHALF(0, 0, bhA, blA);
      MHALF(4, 0, bhA, blA);
    }
    // ================= ss = 1: B buffer B, prefetch B(cs+2) ==============
    {
      if (t < 11) {
        const size_t bbn = BBASE(t * 2 + 2);
#pragma unroll
        for (int n = 0; n < 4; ++n) {
          bhA[n] = *(const bf16x8*)(qhp + bbn + (size_t)n * 512);
          blA[n] = *(const bf16x8*)(qlp + bbn + (size_t)n * 512);
        }
      }
      MHALF(0, 32, bhB, blB);
      MHALF(4, 32, bhB, blB);
    }

    if (t < 11) {
      STAGE(cur ^ 1, (t + 1) * 64);
    }
    __syncthreads();
  }
#undef MHALF
#undef STAGE
#undef BBASE

  // Reduction: C/D layout col = l16 (group), row = lk*4 + reg (token).
#pragma unroll
  for (int m = 0; m < 8; ++m) {
    const int tokbase = s0 + m * 16 + lk * 4;
#pragma unroll
    for (int r = 0; r < 4; ++r) {
      const int tok = tokbase + r;
      float m1 = -3.402823466e38f, m2 = -3.402823466e38f;
      int i1 = 0;
#pragma unroll
      for (int n = 0; n < 4; ++n) {
        float v = acc[m][n][r];
        int g = n * 16 + l16;
        if (v > m1) { m2 = m1; m1 = v; i1 = g; }
        else if (v > m2) m2 = v;
      }
#pragma unroll
      for (int off = 1; off <= 8; off <<= 1) {
        float om1 = __shfl_xor(m1, off);
        float om2 = __shfl_xor(m2, off);
        int oi1 = __shfl_xor(i1, off);
        if (om1 > m1 || (om1 == m1 && oi1 < i1)) {
          m2 = fmaxf(m1, fmaxf(m2, om2));
          m1 = om1; i1 = oi1;
        } else {
          m2 = fmaxf(om1, fmaxf(m2, om2));
        }
      }
      if (l16 == 0) {
        const int bh2 = b * 8 + wn;
        assign_t[((size_t)b * SS + tok) * 8 + wn] = (unsigned char)i1;
        if (m1 - m2 < DELTA) {
          int w = atomicAdd(&scnt[bh2], 1);
          susp[(size_t)bh2 * SS + w] = tok;
        }
      }
    }
  }
}

// ---------------------------------------------------------------------------
// K3: exact fp64 rescore, 16-suspect batches.
// ---------------------------------------------------------------------------
__global__ __launch_bounds__(256) void k_rescore(
    const float* __restrict__ key, const double* __restrict__ qk64,
    const int* __restrict__ susp, const int* __restrict__ scnt,
    unsigned char* __restrict__ assign_t) {
  __shared__ float krow[16][CC];     // 48KB
  __shared__ double l64[16][64];     // 8KB
  const int bh = blockIdx.x;
  const int cnt = scnt[bh];
  if (cnt == 0) return;
  const int b = bh >> 3, h = bh & 7;
  const int tid = threadIdx.x;
  const int n = tid >> 2, q = tid & 3;
  const double* qrow = qk64 + ((size_t)bh * NN + n) * CC + q * 192;

  for (int i0 = 0; i0 < cnt; i0 += 16) {
    const int nb = (cnt - i0 < 16) ? (cnt - i0) : 16;
    for (int r = 0; r < nb; ++r) {
      const int s = susp[(size_t)bh * SS + i0 + r];
      for (int u = tid; u < CC; u += 256)
        krow[r][u] = key[((size_t)b * SS + s) * CC + u];
    }
    __syncthreads();

    double acc[16];
#pragma unroll
    for (int r = 0; r < 16; ++r) acc[r] = 0.0;
    for (int c4 = 0; c4 < 48; ++c4) {
      const double w0 = qrow[c4 * 4 + 0];
      const double w1 = qrow[c4 * 4 + 1];
      const double w2 = qrow[c4 * 4 + 2];
      const double w3 = qrow[c4 * 4 + 3];
#pragma unroll
      for (int r = 0; r < 16; ++r) {
        float4 k4 = *(const float4*)&krow[r][q * 192 + c4 * 4];
        acc[r] += w0 * (double)k4.x;
        acc[r] += w1 * (double)k4.y;
        acc[r] += w2 * (double)k4.z;
        acc[r] += w3 * (double)k4.w;
      }
    }
#pragma unroll
    for (int r = 0; r < 16; ++r) {
      acc[r] += __shfl_xor(acc[r], 1);
      acc[r] += __shfl_xor(acc[r], 2);
    }
    if (q == 0) {
#pragma unroll
      for (int r = 0; r < 16; ++r) l64[r][n] = acc[r];
    }
    __syncthreads();
    if (tid < nb) {
      double best = l64[tid][0];
      int bi = 0;
      for (int n2 = 1; n2 < 64; ++n2)
        if (l64[tid][n2] > best) { best = l64[tid][n2]; bi = n2; }
      const int s = susp[(size_t)bh * SS + i0 + tid];
      assign_t[((size_t)b * SS + s) * 8 + h] = (unsigned char)bi;
    }
    __syncthreads();
  }
}

// ---------------------------------------------------------------------------
// K4: per-(b,h,n) token counts. Block per bh.
// ---------------------------------------------------------------------------
__global__ __launch_bounds__(256) void k_counts(
    const unsigned char* __restrict__ assign_t, int* __restrict__ counts) {
  __shared__ int hist[64];
  const int bh = blockIdx.x;
  const int b = bh >> 3, h = bh & 7;
  const int tid = threadIdx.x;
  if (tid < 64) hist[tid] = 0;
  __syncthreads();
  for (int s = tid; s < SS; s += 256)
    atomicAdd(&hist[assign_t[((size_t)b * SS + s) * 8 + h]], 1);
  __syncthreads();
  if (tid < 64) counts[bh * 64 + tid] = hist[tid];
}

// ---------------------------------------------------------------------------
// K4b: 8-batch key slice -> bf16 (RNE). Called twice.
// ---------------------------------------------------------------------------
__global__ __launch_bounds__(256) void k_convert(
    const float* __restrict__ keyhalf, unsigned short* __restrict__ kb16) {
  const int n8 = 8 * SS * CC / 8;    // 3,145,728 u16x8 outputs
  int i = blockIdx.x * 256 + threadIdx.x;
  const int stride = gridDim.x * 256;
  for (; i < n8; i += stride) {
    float4 a = ((const float4*)keyhalf)[i * 2];
    float4 b = ((const float4*)keyhalf)[i * 2 + 1];
    u16x8 r;
    r[0] = f2bf(a.x); r[1] = f2bf(a.y); r[2] = f2bf(a.z); r[3] = f2bf(a.w);
    r[4] = f2bf(b.x); r[5] = f2bf(b.y); r[6] = f2bf(b.z); r[7] = f2bf(b.w);
    *(u16x8*)(kb16 + (size_t)i * 8) = r;
  }
}

// ---------------------------------------------------------------------------
// K5: stable counting-sort permutation. One wave per (b,h).
// ---------------------------------------------------------------------------
__global__ __launch_bounds__(64) void k_rank(
    const unsigned char* __restrict__ assign_t, const int* __restrict__ counts,
    int* __restrict__ offsets, int* __restrict__ perm) {
  __shared__ int base[64];
  const int bh = blockIdx.x;     // b*8 + h
  const int b = bh >> 3, h = bh & 7;
  const int lane = threadIdx.x;

  int cn = counts[bh * 64 + lane];
  int off = cn;
#pragma unroll
  for (int d = 1; d < 64; d <<= 1) {
    int t = __shfl_up(off, d);
    if (lane >= d) off += t;
  }
  off -= cn;  // exclusive prefix
  offsets[bh * 64 + lane] = off;
  base[lane] = off;

  for (int c = 0; c < SS / 64; ++c) {
    const int s = c * 64 + lane;
    const int g = (int)assign_t[((size_t)b * SS + s) * 8 + h];
    unsigned long long m = ~0ull;
#pragma unroll
    for (int k = 0; k < 6; ++k) {
      unsigned long long bk = __ballot((g >> k) & 1);
      m &= ((g >> k) & 1) ? bk : ~bk;
    }
    const int leader = __ffsll((unsigned long long)m) - 1;
    const int rankin = __popcll(m & ((1ull << lane) - 1ull));
    int baseo = 0;
    if (lane == leader) {
      baseo = base[g];
      base[g] = baseo + __popcll(m);
    }
    baseo = __shfl(baseo, leader);
    perm[(size_t)bh * SS + baseo + rankin] = s;
  }
}

// ---------------------------------------------------------------------------
// K6: permuted gather over bf16 half-copy (8 batches). One wave per (b,h,n).
// ---------------------------------------------------------------------------
__global__ __launch_bounds__(64) void k_gatherp(
    const unsigned short* __restrict__ kb16, const int* __restrict__ perm,
    const int* __restrict__ offsets, const int* __restrict__ counts,
    float* __restrict__ gsum, int b0) {
  const int bid = blockIdx.x;        // local: bl*512 + h*64 + n, bl in [0,8)
  const int bl = bid >> 9;           // local batch
  const int gbid = b0 * 512 + bid;   // global (b*512 + h*64 + n)
  const int bh = gbid >> 6;
  const int lane = threadIdx.x;

  const int off = offsets[gbid];
  const int cnt = counts[gbid];
  const int* pl = perm + (size_t)bh * SS + off;
  const unsigned short* kb = kb16 + (size_t)bl * SS * CC;

  float4 a0 = {0.f, 0.f, 0.f, 0.f}, b0v = a0, c0 = a0;
  int j = 0;
  for (; j + 3 < cnt; j += 4) {
    const int s0 = pl[j], s1 = pl[j + 1], s2 = pl[j + 2], s3 = pl[j + 3];
    const ushort4* k0 = (const ushort4*)(kb + (size_t)s0 * CC);
    const ushort4* k1 = (const ushort4*)(kb + (size_t)s1 * CC);
    const ushort4* k2 = (const ushort4*)(kb + (size_t)s2 * CC);
    const ushort4* k3 = (const ushort4*)(kb + (size_t)s3 * CC);
    ushort4 x0 = k0[lane], x1 = k0[lane + 64], x2 = k0[lane + 128];
    ushort4 y0 = k1[lane], y1 = k1[lane + 64], y2 = k1[lane + 128];
    ushort4 z0 = k2[lane], z1 = k2[lane + 64], z2 = k2[lane + 128];
    ushort4 w0 = k3[lane], w1 = k3[lane + 64], w2 = k3[lane + 128];
    a0.x += bf2f(x0.x); a0.y += bf2f(x0.y); a0.z += bf2f(x0.z); a0.w += bf2f(x0.w);
    b0v.x += bf2f(x1.x); b0v.y += bf2f(x1.y); b0v.z += bf2f(x1.z); b0v.w += bf2f(x1.w);
    c0.x += bf2f(x2.x); c0.y += bf2f(x2.y); c0.z += bf2f(x2.z); c0.w += bf2f(x2.w);
    a0.x += bf2f(y0.x); a0.y += bf2f(y0.y); a0.z += bf2f(y0.z); a0.w += bf2f(y0.w);
    b0v.x += bf2f(y1.x); b0v.y += bf2f(y1.y); b0v.z += bf2f(y1.z); b0v.w += bf2f(y1.w);
    c0.x += bf2f(y2.x); c0.y += bf2f(y2.y); c0.z += bf2f(y2.z); c0.w += bf2f(y2.w);
    a0.x += bf2f(z0.x); a0.y += bf2f(z0.y); a0.z += bf2f(z0.z); a0.w += bf2f(z0.w);
    b0v.x += bf2f(z1.x); b0v.y += bf2f(z1.y); b0v.z += bf2f(z1.z); b0v.w += bf2f(z1.w);
    c0.x += bf2f(z2.x); c0.y += bf2f(z2.y); c0.z += bf2f(z2.z); c0.w += bf2f(z2.w);
    a0.x += bf2f(w0.x); a0.y += bf2f(w0.y); a0.z += bf2f(w0.z); a0.w += bf2f(w0.w);
    b0v.x += bf2f(w1.x); b0v.y += bf2f(w1.y); b0v.z += bf2f(w1.z); b0v.w += bf2f(w1.w);
    c0.x += bf2f(w2.x); c0.y += bf2f(w2.y); c0.z += bf2f(w2.z); c0.w += bf2f(w2.w);
  }
  for (; j < cnt; ++j) {
    const int s0 = pl[j];
    const ushort4* k0 = (const ushort4*)(kb + (size_t)s0 * CC);
    ushort4 x0 = k0[lane], x1 = k0[lane + 64], x2 = k0[lane + 128];
    a0.x += bf2f(x0.x); a0.y += bf2f(x0.y); a0.z += bf2f(x0.z); a0.w += bf2f(x0.w);
    b0v.x += bf2f(x1.x); b0v.y += bf2f(x1.y); b0v.z += bf2f(x1.z); b0v.w += bf2f(x1.w);
    c0.x += bf2f(x2.x); c0.y += bf2f(x2.y); c0.z += bf2f(x2.z); c0.w += bf2f(x2.w);
  }
  float4* go = (float4*)(gsum + (size_t)gbid * CC);
  go[lane] = a0; go[lane + 64] = b0v; go[lane + 128] = c0;
}

// ---------------------------------------------------------------------------
// K7a: vr = renorm(gs) @ WvT. Block = 2 rows x 256 j-cols; grid 1536.
// ---------------------------------------------------------------------------
__global__ __launch_bounds__(256) void k_v(
    const float* __restrict__ gsum, const int* __restrict__ counts,
    const float* __restrict__ WvT, float* __restrict__ vrg) {
  __shared__ float gs[2][HH][CC];   // 48KB
  const int tid = threadIdx.x;
  const int rp = blockIdx.x / 3, cs = blockIdx.x % 3;
  const int r0 = rp * 2;

  for (int r = 0; r < 2; ++r) {
    int row = r0 + r, b = row >> 6, n = row & 63;
    for (int h = 0; h < HH; ++h) {
      const float sc = 1.f / (float)(counts[(b * HH + h) * NN + n] + 1);
      const float* src = gsum + ((size_t)(b * HH + h) * NN + n) * CC;
      for (int m = 0; m < 3; ++m)
        gs[r][h][tid + m * 256] = src[tid + m * 256] * sc;
    }
  }
  __syncthreads();

  const int j = cs * 256 + tid;
  const int hj = j / HD;
  float a0 = 0.f, a1 = 0.f;
  const float* wt = WvT + j;
  for (int e4 = 0; e4 < CC / 4; ++e4) {
    const int e = e4 * 4;
    float4 g0 = *(const float4*)&gs[0][hj][e];
    float4 g1 = *(const float4*)&gs[1][hj][e];
    const float w0 = wt[(size_t)e * CC];
    const float w1 = wt[(size_t)(e + 1) * CC];
    const float w2 = wt[(size_t)(e + 2) * CC];
    const float w3 = wt[(size_t)(e + 3) * CC];
    a0 = fmaf(g0.x, w0, a0); a0 = fmaf(g0.y, w1, a0);
    a0 = fmaf(g0.z, w2, a0); a0 = fmaf(g0.w, w3, a0);
    a1 = fmaf(g1.x, w0, a1); a1 = fmaf(g1.y, w1, a1);
    a1 = fmaf(g1.z, w2, a1); a1 = fmaf(g1.w, w3, a1);
  }
  vrg[(size_t)(r0 + 0) * CC + j] = a0;
  vrg[(size_t)(r0 + 1) * CC + j] = a1;
}

// ---------------------------------------------------------------------------
// K7b: out = vr @ WoT + bo. Block = 2 rows x 256 j-cols; grid 1536.
// ---------------------------------------------------------------------------
__global__ __launch_bounds__(256) void k_o(
    const float* __restrict__ vrg, const float* __restrict__ WoT,
    const float* __restrict__ bo, float* __restrict__ out) {
  __shared__ float vr[2][CC];   // 6KB
  const int tid = threadIdx.x;
  const int rp = blockIdx.x / 3, cs = blockIdx.x % 3;
  const int r0 = rp * 2;

#pragma unroll
  for (int u = 0; u < 6; ++u) {
    int idx = tid + u * 256;
    int r = idx / CC, c = idx - r * CC;
    vr[r][c] = vrg[(size_t)(r0 + r) * CC + c];
  }
  __syncthreads();

  const int j = cs * 256 + tid;
  float a0 = bo[j], a1 = a0;
  const float* wt = WoT + j;
  for (int e4 = 0; e4 < CC / 4; ++e4) {
    const int e = e4 * 4;
    float4 v0 = *(const float4*)&vr[0][e];
    float4 v1 = *(const float4*)&vr[1][e];
    const float w0 = wt[(size_t)e * CC];
    const float w1 = wt[(size_t)(e + 1) * CC];
    const float w2 = wt[(size_t)(e + 2) * CC];
    const float w3 = wt[(size_t)(e + 3) * CC];
    a0 = fmaf(v0.x, w0, a0); a0 = fmaf(v0.y, w1, a0);
    a0 = fmaf(v0.z, w2, a0); a0 = fmaf(v0.w, w3, a0);
    a1 = fmaf(v1.x, w0, a1); a1 = fmaf(v1.y, w1, a1);
    a1 = fmaf(v1.z, w2, a1); a1 = fmaf(v1.w, w3, a1);
  }
  out[(size_t)(r0 + 0) * CC + j] = a0;
  out[(size_t)(r0 + 1) * CC + j] = a1;
}

// ---------------------------------------------------------------------------
extern "C" void kernel_launch(void* const* d_in, const int* in_sizes, int n_in,
                              void* d_out, int out_size, void* d_ws, size_t ws_size,
                              hipStream_t stream) {
  const float* query = (const float*)d_in[0];
  const float* key   = (const float*)d_in[1];
  const float* Wq    = (const float*)d_in[2];
  const float* Wk    = (const float*)d_in[3];
  const float* Wv    = (const float*)d_in[4];
  const float* Wo    = (const float*)d_in[5];
  const float* bo    = (const float*)d_in[6];
  float* out = (float*)d_out;

  char* ws = (char*)d_ws;
  // layout (bytes), high-water 96,797,184 (< round-1-proven 103MB). Aliasing:
  //   qk64 [0, 48MB)       : live k_fold -> rescore
  //   kb16 [0, 48MB)       : 8-batch bf16 key half, written AFTER rescore, 2x
  //   qhp/qlp [48, 72MB)   : live k_fold -> filter
  //   gsum [48, 72MB)      : aliases qhp/qlp, written by gatherp AFTER filter
  double* qk64           = (double*)(ws);                    // 50331648
  unsigned short* kb16   = (unsigned short*)(ws);            // 50331648 (alias)
  unsigned short* qhp    = (unsigned short*)(ws + 50331648); // 12582912
  unsigned short* qlp    = (unsigned short*)(ws + 62914560); // 12582912
  float* gsum            = (float*)(ws + 50331648);          // 25165824 (alias)
  unsigned char* assign_t= (unsigned char*)(ws + 75497472);  // 524288
  int* susp              = (int*)(ws + 76021760);            // 2097152
  int* scnt              = (int*)(ws + 78118912);            // 512
  int* counts            = (int*)(ws + 78119424);            // 32768
  int* offsets           = (int*)(ws + 78152192);            // 32768
  int* perm              = (int*)(ws + 78184960);            // 2097152
  float* WqT             = (float*)(ws + 80282112);          // 2359296
  float* WvT             = (float*)(ws + 82641408);          // 2359296
  float* WoT             = (float*)(ws + 85000704);          // 2359296
  double* q64g           = (double*)(ws + 87360000);         // 6291456
  float* vrg             = (float*)(ws + 93651456);          // 3145728 -> end 96797184

  hipMemsetAsync(scnt, 0, 512, stream);
  k_transpose<<<576, 256, 0, stream>>>(Wq, WqT);
  k_transpose<<<576, 256, 0, stream>>>(Wv, WvT);
  k_transpose<<<576, 256, 0, stream>>>(Wo, WoT);
  k_q<<<1536, 256, 0, stream>>>(query, WqT, q64g);
  k_fold<<<1536, 256, 0, stream>>>(q64g, Wk, qk64, qhp, qlp);
  k_filter_mfma<<<512, 512, 0, stream>>>(key, qhp, qlp, assign_t, susp, scnt);
  k_rescore<<<128, 256, 0, stream>>>(key, qk64, susp, scnt, assign_t);
  k_counts<<<128, 256, 0, stream>>>(assign_t, counts);
  k_rank<<<128, 64, 0, stream>>>(assign_t, counts, offsets, perm);
  // phase A: batches 0..7 (kb16 overwrites dead qk64)
  k_convert<<<1024, 256, 0, stream>>>(key, kb16);
  k_gatherp<<<4096, 64, 0, stream>>>(kb16, perm, offsets, counts, gsum, 0);
  // phase B: batches 8..15
  k_convert<<<1024, 256, 0, stream>>>(key + (size_t)8 * SS * CC, kb16);
  k_gatherp<<<4096, 64, 0, stream>>>(kb16, perm, offsets, counts, gsum, 8);
  k_v<<<1536, 256, 0, stream>>>(gsum, counts, WvT, vrg);
  k_o<<<1536, 256, 0, stream>>>(vrg, WoT, bo, out);
}